// Round 14
// baseline (201.042 us; speedup 1.0000x reference)
//
#include <hip/hip_runtime.h>
#include <hip/hip_bf16.h>

#define BB 2048
#define NN 256
#define EE 32
#define HH 64

typedef __attribute__((ext_vector_type(8))) short s16x8;   // 8 bf16 = MFMA A/B frag
typedef __attribute__((ext_vector_type(4))) short s16x4;
typedef __attribute__((ext_vector_type(4))) float f32x4;   // MFMA C/D frag

__device__ __forceinline__ unsigned short f32_to_bf16_rne(float f) {
    __hip_bfloat16 h = __float2bfloat16(f);
    return *reinterpret_cast<unsigned short*>(&h);
}
__device__ __forceinline__ float bf16_to_f32(unsigned short h) {
    return __uint_as_float(((unsigned int)h) << 16);
}

// ---------------------------------------------------------------------------
// prep_all [validated r13]: one launch, whole-block role split on blockIdx.
// ---------------------------------------------------------------------------
__global__ __launch_bounds__(256) void prep_all(
    const float* __restrict__ x, const float* __restrict__ A,
    const float* __restrict__ emb, const float* __restrict__ W1,
    const float* __restrict__ b1, const float* __restrict__ W2,
    unsigned short* __restrict__ xh, unsigned short* __restrict__ xl,
    unsigned short* __restrict__ w2h, unsigned short* __restrict__ w2l,
    float* __restrict__ c) {

    __shared__ float aS[NN];
    __shared__ float red[256];
    __shared__ float peS[EE];

    const int bid = blockIdx.x;
    const int t   = threadIdx.x;

    if (bid < 512) {
        const int i4 = (bid * 256 + t) * 4;
        const f32x4 v = *(const f32x4*)(x + i4);
        s16x4 hv, lv;
        #pragma unroll
        for (int q = 0; q < 4; ++q) {
            const unsigned short hb = f32_to_bf16_rne(v[q]);
            hv[q] = (short)hb;
            lv[q] = (short)f32_to_bf16_rne(v[q] - bf16_to_f32(hb));
        }
        *(s16x4*)(xh + i4) = hv;
        *(s16x4*)(xl + i4) = lv;
    } else if (bid < 528) {
        const int idx = (bid - 512) * 256 + t;
        const int n = idx >> 6, k = idx & 63;
        const float w = W2[k * HH + n];
        const unsigned short hb = f32_to_bf16_rne(w);
        w2h[n * HH + k] = hb;
        w2l[n * HH + k] = f32_to_bf16_rne(w - bf16_to_f32(hb));
    } else {
        const int i = bid - 528;
        const float a_t = A[t * NN + i];
        aS[t] = a_t;
        red[t] = a_t;
        __syncthreads();
        #pragma unroll
        for (int s = 128; s > 0; s >>= 1) {
            if (t < s) red[t] += red[t + s];
            __syncthreads();
        }
        const float inv = 1.f / (red[0] + 1e-8f);

        const int e = t & 31, jg = t >> 5;
        float part = 0.f;
        #pragma unroll 8
        for (int r = 0; r < 32; ++r) {
            const int j = jg * 32 + r;
            part = fmaf(aS[j], emb[j * EE + e], part);
        }
        __syncthreads();
        red[t] = part;
        __syncthreads();
        if (t < 32) {
            float pe = 0.f;
            #pragma unroll
            for (int g = 0; g < 8; ++g) pe += red[g * 32 + t];
            peS[t] = pe * inv;
        }
        __syncthreads();

        if (t < HH) {
            float ch = b1[t];
            const float* embi = emb + i * EE;
            #pragma unroll 8
            for (int e2 = 0; e2 < EE; ++e2) {
                ch = fmaf(embi[e2], W1[(NN      + e2) * HH + t], ch);
                ch = fmaf(peS[e2],  W1[(NN + EE + e2) * HH + t], ch);
            }
            c[i * HH + t] = ch;
        }
    }
}

// ---------------------------------------------------------------------------
// Fused main (r14): in-fragment epilogues. C-frag layout (validated r7-r13):
// row = wv*64 + rt*16 + lg*4 + rr, col(h) = nt*16 + lm. LN over h = per-lane
// sum over nt + 4-step shfl_xor butterfly over lm (16-lane groups). One LDS
// transpose remains (tr, post-LN1 f32) and it is WAVE-LOCAL: MFMA2 lane reads
// rows wv*64+rt*16+lm — its own wave's quarter — so no barrier after tr write.
// bf16 hi/lo split for MFMA2 A happens in-lane at the tr read. Layer-3 is a
// shfl-reduced dot; stores via unrolled predicated lane-select (rule #20).
// Barriers: 3 (was 9). LDS round-trips: 1 (was ~3). acc1/accE arrays gone.
// ---------------------------------------------------------------------------
__global__ __launch_bounds__(256, 2) void fused_main(
    const unsigned short* __restrict__ xh, const unsigned short* __restrict__ xl,
    const float* __restrict__ A, const float* __restrict__ W1,
    const float* __restrict__ c,
    const unsigned short* __restrict__ w2h, const unsigned short* __restrict__ w2l,
    const float* __restrict__ g1, const float* __restrict__ bt1,
    const float* __restrict__ b2,
    const float* __restrict__ g2, const float* __restrict__ bt2,
    const float* __restrict__ W3, const float* __restrict__ b3,
    float* __restrict__ out) {

    __shared__ float smem[16384];      // 64 KB union: B1 (fold) / tr (f32)
    __shared__ float aS[NN];
    unsigned short* Bh = (unsigned short*)smem;   // 32 frags * 512 shorts
    unsigned short* Bl = Bh + 32 * 512;
    float* tr = smem;                             // [256][64] swizzled, post-LN1

    const int t  = threadIdx.x;
    const int i  = blockIdx.x & 255;
    const int b0 = (blockIdx.x >> 8) * 256;

    const int l  = t & 63;
    const int wv = t >> 6;
    const int lg = l >> 4;
    const int lm = l & 15;

    aS[t] = A[t * NN + i];
    __syncthreads();

    // ---- fold W1s = diag(A[:,i])*W1 into frag-linear split-bf16 LDS [r13] ----
    #pragma unroll
    for (int fr = 0; fr < 8; ++fr) {
        const int f  = wv * 8 + fr;            // f = kb*4 + nt
        const int kb = f >> 2, nt = f & 3;
        const int h  = nt * 16 + lm;
        const int jb = kb * 32 + lg * 8;
        s16x8 hv, lv;
        #pragma unroll
        for (int w = 0; w < 8; ++w) {
            const int j = jb + w;
            const float pw = aS[j] * W1[j * HH + h];
            const unsigned short hb = f32_to_bf16_rne(pw);
            hv[w] = (short)hb;
            lv[w] = (short)f32_to_bf16_rne(pw - bf16_to_f32(hb));
        }
        *(s16x8*)(Bh + f * 512 + l * 8) = hv;
        *(s16x8*)(Bl + f * 512 + l * 8) = lv;
    }
    __syncthreads();

    // ---- MFMA1: 8 kb x 4 rt x 4 nt x 3 terms [r13] ----
    f32x4 acc[4][4];
    #pragma unroll
    for (int rt = 0; rt < 4; ++rt)
        #pragma unroll
        for (int nt = 0; nt < 4; ++nt) {
            acc[rt][nt][0] = 0.f; acc[rt][nt][1] = 0.f;
            acc[rt][nt][2] = 0.f; acc[rt][nt][3] = 0.f;
        }

    const int rowbase = b0 + wv * 64;
    for (int kb = 0; kb < 8; ++kb) {
        s16x8 bh[4], bl[4];
        #pragma unroll
        for (int nt = 0; nt < 4; ++nt) {
            const int sbase = ((kb * 4 + nt) * 64 + l) * 8;
            bh[nt] = *(const s16x8*)(Bh + sbase);
            bl[nt] = *(const s16x8*)(Bl + sbase);
        }
        const int koff = kb * 32 + lg * 8;
        #pragma unroll
        for (int rt = 0; rt < 4; ++rt) {
            const int row = rowbase + rt * 16 + lm;
            const s16x8 ah = *(const s16x8*)(xh + row * NN + koff);
            const s16x8 al = *(const s16x8*)(xl + row * NN + koff);
            #pragma unroll
            for (int nt = 0; nt < 4; ++nt) {
                acc[rt][nt] = __builtin_amdgcn_mfma_f32_16x16x32_bf16(ah, bh[nt], acc[rt][nt], 0, 0, 0);
                acc[rt][nt] = __builtin_amdgcn_mfma_f32_16x16x32_bf16(ah, bl[nt], acc[rt][nt], 0, 0, 0);
                acc[rt][nt] = __builtin_amdgcn_mfma_f32_16x16x32_bf16(al, bh[nt], acc[rt][nt], 0, 0, 0);
            }
        }
    }

    // ---- in-fragment epilogue 1: +c, LN1 (shfl), leaky (r14 new) ----
    float cr[4], g1r[4], bt1r[4];
    #pragma unroll
    for (int nt = 0; nt < 4; ++nt) {
        const int h = nt * 16 + lm;
        cr[nt]   = c[i * HH + h];
        g1r[nt]  = g1[h];
        bt1r[nt] = bt1[h];
    }
    #pragma unroll
    for (int rt = 0; rt < 4; ++rt)
        #pragma unroll
        for (int nt = 0; nt < 4; ++nt)
            #pragma unroll
            for (int rr = 0; rr < 4; ++rr)
                acc[rt][nt][rr] += cr[nt];

    float mm[4][4], iv[4][4];
    #pragma unroll
    for (int rt = 0; rt < 4; ++rt)
        #pragma unroll
        for (int rr = 0; rr < 4; ++rr) {
            float s = acc[rt][0][rr] + acc[rt][1][rr] + acc[rt][2][rr] + acc[rt][3][rr];
            s += __shfl_xor(s, 1); s += __shfl_xor(s, 2);
            s += __shfl_xor(s, 4); s += __shfl_xor(s, 8);
            mm[rt][rr] = s * 0.015625f;            // /64
        }
    #pragma unroll
    for (int rt = 0; rt < 4; ++rt)
        #pragma unroll
        for (int rr = 0; rr < 4; ++rr) {
            float v = 0.f;
            #pragma unroll
            for (int nt = 0; nt < 4; ++nt) {
                const float d = acc[rt][nt][rr] - mm[rt][rr];
                v = fmaf(d, d, v);
            }
            v += __shfl_xor(v, 1); v += __shfl_xor(v, 2);
            v += __shfl_xor(v, 4); v += __shfl_xor(v, 8);
            iv[rt][rr] = rsqrtf(v * 0.015625f + 1e-5f);
        }
    #pragma unroll
    for (int rt = 0; rt < 4; ++rt)
        #pragma unroll
        for (int nt = 0; nt < 4; ++nt)
            #pragma unroll
            for (int rr = 0; rr < 4; ++rr) {
                const float u = (acc[rt][nt][rr] - mm[rt][rr]) * iv[rt][rr] * g1r[nt] + bt1r[nt];
                acc[rt][nt][rr] = (u >= 0.f) ? u : 0.2f * u;
            }

    __syncthreads();   // ALL waves done reading B1; safe to overlay tr

    // ---- tr write: post-LN1 f32, swizzled, wave-local quarter ----
    #pragma unroll
    for (int rt = 0; rt < 4; ++rt)
        #pragma unroll
        for (int nt = 0; nt < 4; ++nt)
            #pragma unroll
            for (int rr = 0; rr < 4; ++rr) {
                const int wr  = wv * 64 + rt * 16 + lg * 4 + rr;
                const int col = nt * 16 + lm;
                const int q   = col >> 2;
                tr[wr * 64 + (((q ^ (wr & 15)) << 2) | (col & 3))] = acc[rt][nt][rr];
            }
    // NO barrier: MFMA2 below reads only this wave's own rows.

    // ---- MFMA2: A from tr (in-lane bf16 split), B from global w2h/w2l ----
    f32x4 acc2[4][4];
    #pragma unroll
    for (int rt = 0; rt < 4; ++rt)
        #pragma unroll
        for (int nt = 0; nt < 4; ++nt) {
            acc2[rt][nt][0] = 0.f; acc2[rt][nt][1] = 0.f;
            acc2[rt][nt][2] = 0.f; acc2[rt][nt][3] = 0.f;
        }
    #pragma unroll
    for (int kk = 0; kk < 2; ++kk) {
        s16x8 b2hf[4], b2lf[4];
        #pragma unroll
        for (int nt = 0; nt < 4; ++nt) {
            const int off = (nt * 16 + lm) * HH + kk * 32 + lg * 8;
            b2hf[nt] = *(const s16x8*)(w2h + off);
            b2lf[nt] = *(const s16x8*)(w2l + off);
        }
        #pragma unroll
        for (int rt = 0; rt < 4; ++rt) {
            const int R   = wv * 64 + rt * 16 + lm;   // A row = this wave's tile
            const int swz = R & 15;
            const int q0  = kk * 8 + lg * 2;          // h = kk*32 + lg*8 + e
            const f32x4 va = *(const f32x4*)&tr[R * 64 + (((q0    ) ^ swz) << 2)];
            const f32x4 vb = *(const f32x4*)&tr[R * 64 + (((q0 + 1) ^ swz) << 2)];
            s16x8 a2h, a2l;
            #pragma unroll
            for (int e = 0; e < 4; ++e) {
                unsigned short hb = f32_to_bf16_rne(va[e]);
                a2h[e]     = (short)hb;
                a2l[e]     = (short)f32_to_bf16_rne(va[e] - bf16_to_f32(hb));
                hb = f32_to_bf16_rne(vb[e]);
                a2h[4 + e] = (short)hb;
                a2l[4 + e] = (short)f32_to_bf16_rne(vb[e] - bf16_to_f32(hb));
            }
            #pragma unroll
            for (int nt = 0; nt < 4; ++nt) {
                acc2[rt][nt] = __builtin_amdgcn_mfma_f32_16x16x32_bf16(a2h, b2hf[nt], acc2[rt][nt], 0, 0, 0);
                acc2[rt][nt] = __builtin_amdgcn_mfma_f32_16x16x32_bf16(a2h, b2lf[nt], acc2[rt][nt], 0, 0, 0);
                acc2[rt][nt] = __builtin_amdgcn_mfma_f32_16x16x32_bf16(a2l, b2hf[nt], acc2[rt][nt], 0, 0, 0);
            }
        }
    }

    // ---- in-fragment epilogue 2: +b2, LN2 (shfl), leaky, W3 dot, store ----
    float b2r[4], g2r[4], bt2r[4], w30[4], w31[4];
    #pragma unroll
    for (int nt = 0; nt < 4; ++nt) {
        const int h = nt * 16 + lm;
        b2r[nt]  = b2[h];
        g2r[nt]  = g2[h];
        bt2r[nt] = bt2[h];
        w30[nt]  = W3[h * 2 + 0];
        w31[nt]  = W3[h * 2 + 1];
    }
    #pragma unroll
    for (int rt = 0; rt < 4; ++rt)
        #pragma unroll
        for (int nt = 0; nt < 4; ++nt)
            #pragma unroll
            for (int rr = 0; rr < 4; ++rr)
                acc2[rt][nt][rr] += b2r[nt];

    #pragma unroll
    for (int rt = 0; rt < 4; ++rt)
        #pragma unroll
        for (int rr = 0; rr < 4; ++rr) {
            float s = acc2[rt][0][rr] + acc2[rt][1][rr] + acc2[rt][2][rr] + acc2[rt][3][rr];
            s += __shfl_xor(s, 1); s += __shfl_xor(s, 2);
            s += __shfl_xor(s, 4); s += __shfl_xor(s, 8);
            mm[rt][rr] = s * 0.015625f;
        }
    #pragma unroll
    for (int rt = 0; rt < 4; ++rt)
        #pragma unroll
        for (int rr = 0; rr < 4; ++rr) {
            float v = 0.f;
            #pragma unroll
            for (int nt = 0; nt < 4; ++nt) {
                const float d = acc2[rt][nt][rr] - mm[rt][rr];
                v = fmaf(d, d, v);
            }
            v += __shfl_xor(v, 1); v += __shfl_xor(v, 2);
            v += __shfl_xor(v, 4); v += __shfl_xor(v, 8);
            iv[rt][rr] = rsqrtf(v * 0.015625f + 1e-5f);
        }

    float o0[4][4], o1[4][4];
    #pragma unroll
    for (int rt = 0; rt < 4; ++rt)
        #pragma unroll
        for (int rr = 0; rr < 4; ++rr) {
            float p0 = 0.f, p1 = 0.f;
            #pragma unroll
            for (int nt = 0; nt < 4; ++nt) {
                float u = (acc2[rt][nt][rr] - mm[rt][rr]) * iv[rt][rr] * g2r[nt] + bt2r[nt];
                u = (u >= 0.f) ? u : 0.2f * u;
                p0 = fmaf(u, w30[nt], p0);
                p1 = fmaf(u, w31[nt], p1);
            }
            p0 += __shfl_xor(p0, 1); p0 += __shfl_xor(p0, 2);
            p0 += __shfl_xor(p0, 4); p0 += __shfl_xor(p0, 8);
            p1 += __shfl_xor(p1, 1); p1 += __shfl_xor(p1, 2);
            p1 += __shfl_xor(p1, 4); p1 += __shfl_xor(p1, 8);
            o0[rt][rr] = p0;
            o1[rt][rr] = p1;
        }

    // predicated lane-select (static indices only — rule #20)
    float so0 = 0.f, so1 = 0.f;
    #pragma unroll
    for (int rt = 0; rt < 4; ++rt)
        #pragma unroll
        for (int rr = 0; rr < 4; ++rr)
            if (lm == rt * 4 + rr) { so0 = o0[rt][rr]; so1 = o1[rt][rr]; }

    const int rowg = b0 + wv * 64 + (lm >> 2) * 16 + lg * 4 + (lm & 3);
    out[rowg * NN + i]           = so0 + b3[0];
    out[BB * NN + rowg * NN + i] = so1 + b3[1];
}

extern "C" void kernel_launch(void* const* d_in, const int* in_sizes, int n_in,
                              void* d_out, int out_size, void* d_ws, size_t ws_size,
                              hipStream_t stream) {
    const float* x   = (const float*)d_in[0];
    const float* A   = (const float*)d_in[1];
    const float* emb = (const float*)d_in[2];
    const float* W1  = (const float*)d_in[3];
    const float* b1  = (const float*)d_in[4];
    const float* g1  = (const float*)d_in[5];
    const float* bt1 = (const float*)d_in[6];
    const float* W2  = (const float*)d_in[7];
    const float* b2  = (const float*)d_in[8];
    const float* g2  = (const float*)d_in[9];
    const float* bt2 = (const float*)d_in[10];
    const float* W3  = (const float*)d_in[11];
    const float* b3  = (const float*)d_in[12];
    float* out = (float*)d_out;

    // ws carve: c (64 KB) | xh (1 MB) | xl (1 MB) | w2h (8 KB) | w2l (8 KB)
    float* c = (float*)d_ws;
    unsigned short* xhp = (unsigned short*)(c + NN * HH);
    unsigned short* xlp = xhp + BB * NN;
    unsigned short* w2hp = xlp + BB * NN;
    unsigned short* w2lp = w2hp + HH * HH;

    prep_all<<<784, 256, 0, stream>>>(x, A, emb, W1, b1, W2,
                                      xhp, xlp, w2hp, w2lp, c);
    fused_main<<<NN * (BB / 256), 256, 0, stream>>>(
        xhp, xlp, A, W1, c, w2hp, w2lp, g1, bt1, b2, g2, bt2, W3, b3, out);
}